// Round 5
// baseline (1359.339 us; speedup 1.0000x reference)
//
#include <hip/hip_runtime.h>
#include <stdint.h>

#define N_NODES 100000
#define D 128
#define BN 64                        // nodes per bucket
#define NB ((N_NODES + BN - 1) / BN) // 1563 buckets
#define NR 32                        // counter replicas per bucket
#define CAPR 128                     // per-(bucket,replica) capacity (mean 32, sigma 5.7 -> 17 sigma)
#define HROW 133                     // hNacc row stride in floats (bank-spread: 5*lr mod 32 distinct)
#define HSZ (BN * HROW)              // 8512 floats = 34 KB

typedef short bf16x8 __attribute__((ext_vector_type(8)));
typedef float f32x4 __attribute__((ext_vector_type(4)));

__device__ __forceinline__ unsigned short f2bf(float f) {
    unsigned int x = __float_as_uint(f);
    unsigned int r = x + 0x7fffu + ((x >> 16) & 1u);
    return (unsigned short)(r >> 16);
}

// ---- fused prep: every conv block also handles ~128 edges -----------------
// [0,cblocks): h->bf16 conv + per-edge partition into replicated buckets
// [cblocks, cblocks+16): W-pack
// Replica = bid & 31: same-address atomic chains are 32 deep, not 1024.
__global__ __launch_bounds__(256) void prep_k(
    const float* __restrict__ h, unsigned short* __restrict__ h_bf,
    const float* __restrict__ W, unsigned short* __restrict__ Wf,
    const int* __restrict__ src, const int* __restrict__ dst,
    int* __restrict__ cnt, unsigned int* __restrict__ pairs,
    int n_edges, int cblocks, int epb)
{
    int bid = blockIdx.x;
    int t = threadIdx.x;

    if (bid < cblocks) {
        // issue the conv load first (latency overlaps edge work)
        size_t base = ((size_t)bid * 256 + t) * 4;
        float4 v = *(const float4*)(h + base);

        int rep = bid & (NR - 1);
        for (int i = t; i < epb; i += 256) {
            int e = bid * epb + i;
            if (e < n_edges) {
                int d = dst[e], bkt = d >> 6;
                int slot = atomicAdd(&cnt[bkt * NR + rep], 1);
                if (slot < CAPR)
                    pairs[((size_t)bkt * NR + rep) * CAPR + slot] =
                        (unsigned int)src[e] | ((unsigned int)(d & 63) << 17);
            }
        }

        // ---- h fp32 -> bf16
        ushort4 o;
        o.x = f2bf(v.x); o.y = f2bf(v.y); o.z = f2bf(v.z); o.w = f2bf(v.w);
        *(ushort4*)(h_bf + base) = o;
    } else {
        // ---- pack W [256][128] fp32 -> bf16 B-fragment order ----
        // frag f = kt*8+ct; lane l holds W[kt*32+(l>>4)*8+j][ct*16+(l&15)]
        int gid = (bid - cblocks) * 256 + t;
        if (gid < 64 * 64) {
            int f = gid >> 6, l = gid & 63;
            int kt = f >> 3, ct = f & 7;
            int n = ct * 16 + (l & 15);
            int kb = kt * 32 + (l >> 4) * 8;
            #pragma unroll
            for (int j = 0; j < 8; ++j)
                Wf[(size_t)f * 512 + l * 8 + j] = f2bf(W[(size_t)(kb + j) * D + n]);
        }
    }
}

// ---- fused aggregate + GEMM: block = bucket of 64 nodes, 512 threads ------
// Phase 1: stream edges, LDS ds_add_f32 accumulate (order-free, no sort,
//          no scan, 2 barriers total). Feature f of node n lives at
//          hNacc[n*133 + (f&3)*33 + (f>>2)]; slot n*133+32 counts degree.
// Phase 2: 8-wave MFMA, neighbor A-frag built on the fly (mean + bf16 cvt).
__global__ __launch_bounds__(512, 8) void aggemm_k(
    const unsigned short* __restrict__ h_bf, const unsigned int* __restrict__ pairs,
    const int* __restrict__ cnt_g, const unsigned short* __restrict__ Wf,
    const float* __restrict__ bias, float* __restrict__ out)
{
    __shared__ float hNacc[HSZ];   // 34 KB -> 4 blocks/CU

    int t = threadIdx.x;
    int b = blockIdx.x;
    int wv = t >> 6, l = t & 63;
    int half = l >> 5, j = l & 31;   // lane covers features 4j..4j+3

    // zero accumulator
    for (int i = t; i < HSZ; i += 512) hNacc[i] = 0.f;
    __syncthreads();

#define ACC(p, u) { \
        float* a_ = hNacc + (int)((p) >> 17) * HROW; \
        atomicAdd(a_ + j,      __uint_as_float((u).x << 16)); \
        atomicAdd(a_ + 33 + j, __uint_as_float((u).x & 0xffff0000u)); \
        atomicAdd(a_ + 66 + j, __uint_as_float((u).y << 16)); \
        atomicAdd(a_ + 99 + j, __uint_as_float((u).y & 0xffff0000u)); \
        if (j == 0) atomicAdd(a_ + 32, 1.0f); \
    }

    // edge accumulate: wave wv owns replica segments 4wv..4wv+3.
    // Half-wave = one edge; each lane loads 8B (4 feats) of the src row.
    #pragma unroll
    for (int r = 0; r < 4; ++r) {
        int seg = wv * 4 + r;
        int c = cnt_g[b * NR + seg];
        if (c > CAPR) c = CAPR;
        const unsigned int* ps = pairs + ((size_t)b * NR + seg) * CAPR;
        int i = 0;
        for (; i + 8 <= c; i += 8) {          // 4 pairs = 8 edges in flight
            unsigned int p0 = ps[i     + half];
            unsigned int p1 = ps[i + 2 + half];
            unsigned int p2 = ps[i + 4 + half];
            unsigned int p3 = ps[i + 6 + half];
            uint2 u0 = *(const uint2*)(h_bf + (size_t)(p0 & 0x1FFFF) * D + j * 4);
            uint2 u1 = *(const uint2*)(h_bf + (size_t)(p1 & 0x1FFFF) * D + j * 4);
            uint2 u2 = *(const uint2*)(h_bf + (size_t)(p2 & 0x1FFFF) * D + j * 4);
            uint2 u3 = *(const uint2*)(h_bf + (size_t)(p3 & 0x1FFFF) * D + j * 4);
            ACC(p0, u0); ACC(p1, u1); ACC(p2, u2); ACC(p3, u3);
        }
        for (; i + 2 <= c; i += 2) {          // single pair
            unsigned int p = ps[i + half];
            uint2 u = *(const uint2*)(h_bf + (size_t)(p & 0x1FFFF) * D + j * 4);
            ACC(p, u);
        }
        if (i < c) {                          // odd tail: half 0 only
            if (half == 0) {
                unsigned int p = ps[i];
                uint2 u = *(const uint2*)(h_bf + (size_t)(p & 0x1FFFF) * D + j * 4);
                ACC(p, u);
            }
        }
    }
#undef ACC
    __syncthreads();

    // ---- GEMM: wave w -> row-tile (w>>1), col-half (w&1) ------------------
    int rt = wv >> 1, ch = wv & 1;
    int lrow = l & 15, lq = l >> 4;
    int lr = rt * 16 + lrow;                       // local A row
    int nbase = b * BN;
    int r0 = nbase + lr; if (r0 > N_NODES - 1) r0 = N_NODES - 1;

    float degv = hNacc[lr * HROW + 32];
    float invd = degv > 0.f ? 1.0f / degv : 0.f;

    f32x4 acc[4];
    #pragma unroll
    for (int c = 0; c < 4; ++c) acc[c] = (f32x4){0.f, 0.f, 0.f, 0.f};

    const unsigned short* wf_lane = Wf + l * 8;

    #pragma unroll
    for (int kt = 0; kt < 8; ++kt) {
        int ko = (kt & 3) * 32 + lq * 8;
        bf16x8 a;
        if (kt < 4) {
            a = *(const bf16x8*)(h_bf + (size_t)r0 * D + ko);   // self features
        } else {
            #pragma unroll
            for (int m = 0; m < 8; ++m) {                       // neighbor mean
                int f = ko + m;
                float v = hNacc[lr * HROW + (f & 3) * 33 + (f >> 2)] * invd;
                a[m] = (short)f2bf(v);
            }
        }
        #pragma unroll
        for (int c = 0; c < 4; ++c) {
            int ct = ch * 4 + c;
            bf16x8 bfr = *(const bf16x8*)(wf_lane + (size_t)(kt * 8 + ct) * 512);
            acc[c] = __builtin_amdgcn_mfma_f32_16x16x32_bf16(a, bfr, acc[c], 0, 0, 0);
        }
    }

    int col = l & 15, q = l >> 4;
    #pragma unroll
    for (int c = 0; c < 4; ++c) {
        int ct = ch * 4 + c;
        float bv = bias[ct * 16 + col];
        #pragma unroll
        for (int r = 0; r < 4; ++r) {
            int row = nbase + rt * 16 + q * 4 + r;
            if (row < N_NODES)
                out[(size_t)row * D + ct * 16 + col] = acc[c][r] + bv;
        }
    }
}

// ---- launch ---------------------------------------------------------------

extern "C" void kernel_launch(void* const* d_in, const int* in_sizes, int n_in,
                              void* d_out, int out_size, void* d_ws, size_t ws_size,
                              hipStream_t stream) {
    const float* h  = (const float*)d_in[0];
    const int* src  = (const int*)d_in[1];
    const int* dst  = (const int*)d_in[2];
    const float* W  = (const float*)d_in[3];
    const float* b  = (const float*)d_in[4];
    float* out      = (float*)d_out;
    int n_edges = in_sizes[1];

    // workspace layout (~51.5 MB)
    char* ws = (char*)d_ws;
    unsigned short* h_bf  = (unsigned short*)ws;                          // 25.6 MB
    unsigned int* pairs   = (unsigned int*)(h_bf + (size_t)N_NODES * D);  // 25.6 MB (NB*NR*CAPR*4)
    unsigned short* Wf    = (unsigned short*)(pairs + (size_t)NB * NR * CAPR); // 64 KB
    int* cnt              = (int*)(Wf + 64 * 512);                        // 200 KB

    hipMemsetAsync(cnt, 0, NB * NR * sizeof(int), stream);

    int cblocks = (int)(((size_t)N_NODES * D / 4 + 255) / 256); // 12500
    int epb = (n_edges + cblocks - 1) / cblocks;                // 128
    hipLaunchKernelGGL(prep_k, dim3(cblocks + 16), dim3(256), 0, stream,
                       h, h_bf, W, Wf, src, dst, cnt, pairs, n_edges, cblocks, epb);

    hipLaunchKernelGGL(aggemm_k, dim3(NB), dim3(512), 0, stream,
                       h_bf, pairs, cnt, Wf, b, out);
}

// Round 6
// 267.910 us; speedup vs baseline: 5.0739x; 5.0739x over previous
//
#include <hip/hip_runtime.h>
#include <stdint.h>

#define N_NODES 100000
#define D 128
#define BN 64                        // nodes per block (GEMM row tile)
#define NB ((N_NODES + BN - 1) / BN) // 1563 blocks
#define CAPN 64                      // per-node edge capacity (mean deg 16; P(deg>=64) ~ 1e-17)
#define HPAD 136                     // hNs row stride in ushorts (272B -> 2-way max on b128 reads)

typedef short bf16x8 __attribute__((ext_vector_type(8)));
typedef float f32x4 __attribute__((ext_vector_type(4)));

__device__ __forceinline__ unsigned short f2bf(float f) {
    unsigned int x = __float_as_uint(f);
    unsigned int r = x + 0x7fffu + ((x >> 16) & 1u);
    return (unsigned short)(r >> 16);
}

// ---- fused prep: conv + per-NODE partition + W-pack -----------------------
// Per-node counters: 1.6M atomics over 100K addresses = 16-deep chains
// (R3 failed at 1024-deep; R4 worked at 32-deep; 16 is trivially cheap).
// Node edge lists land pre-grouped -> aggemm needs no sort at all.
__global__ __launch_bounds__(256) void prep_k(
    const float* __restrict__ h, unsigned short* __restrict__ h_bf,
    const float* __restrict__ W, unsigned short* __restrict__ Wf,
    const int* __restrict__ src, const int* __restrict__ dst,
    int* __restrict__ cnt, unsigned int* __restrict__ pairs,
    int n_edges, int cblocks, int epb)
{
    int bid = blockIdx.x;
    int t = threadIdx.x;

    if (bid < cblocks) {
        // issue the conv load first (latency overlaps edge work)
        size_t base = ((size_t)bid * 256 + t) * 4;
        float4 v = *(const float4*)(h + base);

        // ---- per-edge partition into per-node slots
        for (int i = t; i < epb; i += 256) {
            int e = bid * epb + i;
            if (e < n_edges) {
                int d = dst[e];
                int slot = atomicAdd(&cnt[d], 1);
                if (slot < CAPN)
                    pairs[(size_t)d * CAPN + slot] = (unsigned int)src[e];
            }
        }

        // ---- h fp32 -> bf16
        ushort4 o;
        o.x = f2bf(v.x); o.y = f2bf(v.y); o.z = f2bf(v.z); o.w = f2bf(v.w);
        *(ushort4*)(h_bf + base) = o;
    } else {
        // ---- pack W [256][128] fp32 -> bf16 B-fragment order ----
        // frag f = kt*8+ct; lane l holds W[kt*32+(l>>4)*8+j][ct*16+(l&15)]
        int gid = (bid - cblocks) * 256 + t;
        if (gid < 64 * 64) {
            int f = gid >> 6, l = gid & 63;
            int kt = f >> 3, ct = f & 7;
            int n = ct * 16 + (l & 15);
            int kb = kt * 32 + (l >> 4) * 8;
            #pragma unroll
            for (int j = 0; j < 8; ++j)
                Wf[(size_t)f * 512 + l * 8 + j] = f2bf(W[(size_t)(kb + j) * D + n]);
        }
    }
}

// ---- fused gather + GEMM: block = 64 nodes, 512 threads, 1 barrier --------
// Phase 1: each half-wave owns one node; streams its pre-grouped edge list
//          (contiguous in pairs), unroll-4 uint2 gathers of h_bf rows,
//          mean -> bf16 -> hNs LDS tile. No histogram/scan/scatter.
// Phase 2: 8-wave MFMA: out[64][128] = [h_row | hNs] @ W + b.
__global__ __launch_bounds__(512, 8) void aggemm_k(
    const unsigned short* __restrict__ h_bf, const unsigned int* __restrict__ pairs,
    const int* __restrict__ cnt_g, const unsigned short* __restrict__ Wf,
    const float* __restrict__ bias, float* __restrict__ out)
{
    __shared__ unsigned short hNs[BN][HPAD];  // 17.4 KB

    int t = threadIdx.x;
    int b = blockIdx.x;
    int wv = t >> 6, l = t & 63;
    int half = l >> 5, j = l & 31;   // lane covers features 4j..4j+3
    int nbase = b * BN;

    // gather: pass p, wave wv, half -> local node p*16 + wv*2 + half
    #pragma unroll
    for (int p = 0; p < 4; ++p) {
        int nl = p * 16 + wv * 2 + half;
        int n = nbase + nl;
        int dg = 0;
        if (n < N_NODES) { dg = cnt_g[n]; if (dg > CAPN) dg = CAPN; }
        const unsigned int* ps = pairs + (size_t)(n < N_NODES ? n : 0) * CAPN;
        float a0 = 0.f, a1 = 0.f, a2 = 0.f, a3 = 0.f;
        int i = 0;
        for (; i + 4 <= dg; i += 4) {     // 4 row-gathers in flight per half
            unsigned int s0 = ps[i],     s1 = ps[i + 1];
            unsigned int s2 = ps[i + 2], s3 = ps[i + 3];
            uint2 u0 = *(const uint2*)(h_bf + (size_t)s0 * D + j * 4);
            uint2 u1 = *(const uint2*)(h_bf + (size_t)s1 * D + j * 4);
            uint2 u2 = *(const uint2*)(h_bf + (size_t)s2 * D + j * 4);
            uint2 u3 = *(const uint2*)(h_bf + (size_t)s3 * D + j * 4);
            a0 += (__uint_as_float(u0.x << 16) + __uint_as_float(u1.x << 16))
                + (__uint_as_float(u2.x << 16) + __uint_as_float(u3.x << 16));
            a1 += (__uint_as_float(u0.x & 0xffff0000u) + __uint_as_float(u1.x & 0xffff0000u))
                + (__uint_as_float(u2.x & 0xffff0000u) + __uint_as_float(u3.x & 0xffff0000u));
            a2 += (__uint_as_float(u0.y << 16) + __uint_as_float(u1.y << 16))
                + (__uint_as_float(u2.y << 16) + __uint_as_float(u3.y << 16));
            a3 += (__uint_as_float(u0.y & 0xffff0000u) + __uint_as_float(u1.y & 0xffff0000u))
                + (__uint_as_float(u2.y & 0xffff0000u) + __uint_as_float(u3.y & 0xffff0000u));
        }
        for (; i < dg; ++i) {
            unsigned int s = ps[i];
            uint2 u = *(const uint2*)(h_bf + (size_t)s * D + j * 4);
            a0 += __uint_as_float(u.x << 16);
            a1 += __uint_as_float(u.x & 0xffff0000u);
            a2 += __uint_as_float(u.y << 16);
            a3 += __uint_as_float(u.y & 0xffff0000u);
        }
        float invd = dg > 0 ? 1.0f / (float)dg : 0.f;
        uint2 o;
        o.x = ((unsigned int)f2bf(a1 * invd) << 16) | f2bf(a0 * invd);
        o.y = ((unsigned int)f2bf(a3 * invd) << 16) | f2bf(a2 * invd);
        *(uint2*)(&hNs[nl][j * 4]) = o;   // LDS only; never goes to HBM
    }
    __syncthreads();

    // ---- GEMM: wave wv -> row-tile (wv>>1), col-half (wv&1) ---------------
    int rt = wv >> 1, ch = wv & 1;
    int lrow = l & 15, lq = l >> 4;
    int lr = rt * 16 + lrow;                       // local A row
    int r0 = nbase + lr; if (r0 > N_NODES - 1) r0 = N_NODES - 1;

    f32x4 acc[4];
    #pragma unroll
    for (int c = 0; c < 4; ++c) acc[c] = (f32x4){0.f, 0.f, 0.f, 0.f};

    const unsigned short* wf_lane = Wf + l * 8;

    #pragma unroll
    for (int kt = 0; kt < 8; ++kt) {
        int ko = (kt & 3) * 32 + lq * 8;
        bf16x8 a;
        if (kt < 4)
            a = *(const bf16x8*)(h_bf + (size_t)r0 * D + ko);   // self features
        else
            a = *(const bf16x8*)(&hNs[lr][ko]);                 // neighbor mean
        #pragma unroll
        for (int c = 0; c < 4; ++c) {
            int ct = ch * 4 + c;
            bf16x8 bfr = *(const bf16x8*)(wf_lane + (size_t)(kt * 8 + ct) * 512);
            acc[c] = __builtin_amdgcn_mfma_f32_16x16x32_bf16(a, bfr, acc[c], 0, 0, 0);
        }
    }

    int col = l & 15, q = l >> 4;
    #pragma unroll
    for (int c = 0; c < 4; ++c) {
        int ct = ch * 4 + c;
        float bv = bias[ct * 16 + col];
        #pragma unroll
        for (int r = 0; r < 4; ++r) {
            int row = nbase + rt * 16 + q * 4 + r;
            if (row < N_NODES)
                out[(size_t)row * D + ct * 16 + col] = acc[c][r] + bv;
        }
    }
}

// ---- launch ---------------------------------------------------------------

extern "C" void kernel_launch(void* const* d_in, const int* in_sizes, int n_in,
                              void* d_out, int out_size, void* d_ws, size_t ws_size,
                              hipStream_t stream) {
    const float* h  = (const float*)d_in[0];
    const int* src  = (const int*)d_in[1];
    const int* dst  = (const int*)d_in[2];
    const float* W  = (const float*)d_in[3];
    const float* b  = (const float*)d_in[4];
    float* out      = (float*)d_out;
    int n_edges = in_sizes[1];

    // workspace layout (~51.7 MB)
    char* ws = (char*)d_ws;
    unsigned short* h_bf  = (unsigned short*)ws;                          // 25.6 MB
    unsigned int* pairs   = (unsigned int*)(h_bf + (size_t)N_NODES * D);  // 25.6 MB (N_NODES*CAPN*4)
    unsigned short* Wf    = (unsigned short*)(pairs + (size_t)N_NODES * CAPN); // 64 KB
    int* cnt              = (int*)(Wf + 64 * 512);                        // 400 KB

    hipMemsetAsync(cnt, 0, N_NODES * sizeof(int), stream);

    int cblocks = (int)(((size_t)N_NODES * D / 4 + 255) / 256); // 12500
    int epb = (n_edges + cblocks - 1) / cblocks;                // 128
    hipLaunchKernelGGL(prep_k, dim3(cblocks + 16), dim3(256), 0, stream,
                       h, h_bf, W, Wf, src, dst, cnt, pairs, n_edges, cblocks, epb);

    hipLaunchKernelGGL(aggemm_k, dim3(NB), dim3(512), 0, stream,
                       h_bf, pairs, cnt, Wf, b, out);
}

// Round 7
// 265.129 us; speedup vs baseline: 5.1271x; 1.0105x over previous
//
#include <hip/hip_runtime.h>
#include <stdint.h>

#define N_NODES 100000
#define D 128
#define BN 64                        // nodes per block (GEMM row tile)
#define NB ((N_NODES + BN - 1) / BN) // 1563 blocks
#define CAPN 64                      // per-node edge capacity (mean deg 16; P(deg>=64) ~ 1e-17)
#define HPAD 136                     // hNs row stride in ushorts (272B = 68 words = 4 mod 32 -> conflict-free b128)

typedef short bf16x8 __attribute__((ext_vector_type(8)));
typedef float f32x4 __attribute__((ext_vector_type(4)));

__device__ __forceinline__ unsigned short f2bf(float f) {
    unsigned int x = __float_as_uint(f);
    unsigned int r = x + 0x7fffu + ((x >> 16) & 1u);
    return (unsigned short)(r >> 16);
}
__device__ __forceinline__ float blo(unsigned int u) { return __uint_as_float(u << 16); }
__device__ __forceinline__ float bhi(unsigned int u) { return __uint_as_float(u & 0xffff0000u); }

// ---- fused prep: conv + per-NODE partition + W-pack -----------------------
// Per-node counters: 1.6M atomics over 100K addresses = 16-deep chains
// (R3 failed at 1024-deep; 16-deep is cheap). Edge lists land pre-grouped.
__global__ __launch_bounds__(256) void prep_k(
    const float* __restrict__ h, unsigned short* __restrict__ h_bf,
    const float* __restrict__ W, unsigned short* __restrict__ Wf,
    const int* __restrict__ src, const int* __restrict__ dst,
    int* __restrict__ cnt, unsigned int* __restrict__ pairs,
    int n_edges, int cblocks, int epb)
{
    int bid = blockIdx.x;
    int t = threadIdx.x;

    if (bid < cblocks) {
        // issue the conv load first (latency overlaps edge work)
        size_t base = ((size_t)bid * 256 + t) * 4;
        float4 v = *(const float4*)(h + base);

        // ---- per-edge partition into per-node slots
        for (int i = t; i < epb; i += 256) {
            int e = bid * epb + i;
            if (e < n_edges) {
                int d = dst[e];
                int slot = atomicAdd(&cnt[d], 1);
                if (slot < CAPN)
                    pairs[(size_t)d * CAPN + slot] = (unsigned int)src[e];
            }
        }

        // ---- h fp32 -> bf16
        ushort4 o;
        o.x = f2bf(v.x); o.y = f2bf(v.y); o.z = f2bf(v.z); o.w = f2bf(v.w);
        *(ushort4*)(h_bf + base) = o;
    } else {
        // ---- pack W [256][128] fp32 -> bf16 B-fragment order ----
        // frag f = kt*8+ct; lane l holds W[kt*32+(l>>4)*8+j][ct*16+(l&15)]
        int gid = (bid - cblocks) * 256 + t;
        if (gid < 64 * 64) {
            int f = gid >> 6, l = gid & 63;
            int kt = f >> 3, ct = f & 7;
            int n = ct * 16 + (l & 15);
            int kb = kt * 32 + (l >> 4) * 8;
            #pragma unroll
            for (int j = 0; j < 8; ++j)
                Wf[(size_t)f * 512 + l * 8 + j] = f2bf(W[(size_t)(kb + j) * D + n]);
        }
    }
}

// ---- fused gather + GEMM: block = 64 nodes, 512 threads, 1 barrier --------
// Phase 1: QUARTER-wave (16 lanes x dwordx4 = one 256B row) per node.
//          One wave-instr gathers 4 edges; unroll 4 -> 16 loads in flight
//          per wave (2x the half-wave scheme). Edge indices come in one
//          uint4 load. Mean -> bf16 -> hNs LDS tile.
// Phase 2: 8-wave MFMA: out[64][128] = [h_row | hNs] @ W + b.
__global__ __launch_bounds__(512, 8) void aggemm_k(
    const unsigned short* __restrict__ h_bf, const unsigned int* __restrict__ pairs,
    const int* __restrict__ cnt_g, const unsigned short* __restrict__ Wf,
    const float* __restrict__ bias, float* __restrict__ out)
{
    __shared__ unsigned short hNs[BN][HPAD];  // 17.4 KB

    int t = threadIdx.x;
    int b = blockIdx.x;
    int wv = t >> 6, l = t & 63;
    int q = l >> 4, lq = l & 15;     // quarter-wave id, lane-in-quarter
    int nbase = b * BN;

    // gather: pass p -> local node p*32 + wv*4 + q; lane lq covers feats 8lq..8lq+7
    #pragma unroll
    for (int p = 0; p < 2; ++p) {
        int nl = p * 32 + wv * 4 + q;
        int n = nbase + nl;
        int dg = 0;
        if (n < N_NODES) { dg = cnt_g[n]; if (dg > CAPN) dg = CAPN; }
        const unsigned int* ps = pairs + (size_t)(n < N_NODES ? n : 0) * CAPN;
        float a0 = 0.f, a1 = 0.f, a2 = 0.f, a3 = 0.f;
        float a4 = 0.f, a5 = 0.f, a6 = 0.f, a7 = 0.f;
        int i = 0;
        for (; i + 4 <= dg; i += 4) {         // 4 row-loads in flight per quarter
            uint4 s4 = *(const uint4*)(ps + i);      // 4 edge indices, one load
            uint4 u0 = *(const uint4*)(h_bf + (size_t)s4.x * D + lq * 8);
            uint4 u1 = *(const uint4*)(h_bf + (size_t)s4.y * D + lq * 8);
            uint4 u2 = *(const uint4*)(h_bf + (size_t)s4.z * D + lq * 8);
            uint4 u3 = *(const uint4*)(h_bf + (size_t)s4.w * D + lq * 8);
            a0 += (blo(u0.x) + blo(u1.x)) + (blo(u2.x) + blo(u3.x));
            a1 += (bhi(u0.x) + bhi(u1.x)) + (bhi(u2.x) + bhi(u3.x));
            a2 += (blo(u0.y) + blo(u1.y)) + (blo(u2.y) + blo(u3.y));
            a3 += (bhi(u0.y) + bhi(u1.y)) + (bhi(u2.y) + bhi(u3.y));
            a4 += (blo(u0.z) + blo(u1.z)) + (blo(u2.z) + blo(u3.z));
            a5 += (bhi(u0.z) + bhi(u1.z)) + (bhi(u2.z) + bhi(u3.z));
            a6 += (blo(u0.w) + blo(u1.w)) + (blo(u2.w) + blo(u3.w));
            a7 += (bhi(u0.w) + bhi(u1.w)) + (bhi(u2.w) + bhi(u3.w));
        }
        for (; i < dg; ++i) {
            uint4 u = *(const uint4*)(h_bf + (size_t)ps[i] * D + lq * 8);
            a0 += blo(u.x); a1 += bhi(u.x);
            a2 += blo(u.y); a3 += bhi(u.y);
            a4 += blo(u.z); a5 += bhi(u.z);
            a6 += blo(u.w); a7 += bhi(u.w);
        }
        float invd = dg > 0 ? 1.0f / (float)dg : 0.f;
        uint4 o;
        o.x = ((unsigned int)f2bf(a1 * invd) << 16) | f2bf(a0 * invd);
        o.y = ((unsigned int)f2bf(a3 * invd) << 16) | f2bf(a2 * invd);
        o.z = ((unsigned int)f2bf(a5 * invd) << 16) | f2bf(a4 * invd);
        o.w = ((unsigned int)f2bf(a7 * invd) << 16) | f2bf(a6 * invd);
        *(uint4*)(&hNs[nl][lq * 8]) = o;   // 16B/lane consecutive: conflict-free
    }
    __syncthreads();

    // ---- GEMM: wave wv -> row-tile (wv>>1), col-half (wv&1) ---------------
    int rt = wv >> 1, ch = wv & 1;
    int lrow = l & 15, lqd = l >> 4;
    int lr = rt * 16 + lrow;                       // local A row
    int r0 = nbase + lr; if (r0 > N_NODES - 1) r0 = N_NODES - 1;

    f32x4 acc[4];
    #pragma unroll
    for (int c = 0; c < 4; ++c) acc[c] = (f32x4){0.f, 0.f, 0.f, 0.f};

    const unsigned short* wf_lane = Wf + l * 8;

    #pragma unroll
    for (int kt = 0; kt < 8; ++kt) {
        int ko = (kt & 3) * 32 + lqd * 8;
        bf16x8 a;
        if (kt < 4)
            a = *(const bf16x8*)(h_bf + (size_t)r0 * D + ko);   // self features
        else
            a = *(const bf16x8*)(&hNs[lr][ko]);                 // neighbor mean
        #pragma unroll
        for (int c = 0; c < 4; ++c) {
            int ct = ch * 4 + c;
            bf16x8 bfr = *(const bf16x8*)(wf_lane + (size_t)(kt * 8 + ct) * 512);
            acc[c] = __builtin_amdgcn_mfma_f32_16x16x32_bf16(a, bfr, acc[c], 0, 0, 0);
        }
    }

    int col = l & 15, qd = l >> 4;
    #pragma unroll
    for (int c = 0; c < 4; ++c) {
        int ct = ch * 4 + c;
        float bv = bias[ct * 16 + col];
        #pragma unroll
        for (int r = 0; r < 4; ++r) {
            int row = nbase + rt * 16 + qd * 4 + r;
            if (row < N_NODES)
                out[(size_t)row * D + ct * 16 + col] = acc[c][r] + bv;
        }
    }
}

// ---- launch ---------------------------------------------------------------

extern "C" void kernel_launch(void* const* d_in, const int* in_sizes, int n_in,
                              void* d_out, int out_size, void* d_ws, size_t ws_size,
                              hipStream_t stream) {
    const float* h  = (const float*)d_in[0];
    const int* src  = (const int*)d_in[1];
    const int* dst  = (const int*)d_in[2];
    const float* W  = (const float*)d_in[3];
    const float* b  = (const float*)d_in[4];
    float* out      = (float*)d_out;
    int n_edges = in_sizes[1];

    // workspace layout (~51.7 MB)
    char* ws = (char*)d_ws;
    unsigned short* h_bf  = (unsigned short*)ws;                          // 25.6 MB
    unsigned int* pairs   = (unsigned int*)(h_bf + (size_t)N_NODES * D);  // 25.6 MB (N_NODES*CAPN*4)
    unsigned short* Wf    = (unsigned short*)(pairs + (size_t)N_NODES * CAPN); // 64 KB
    int* cnt              = (int*)(Wf + 64 * 512);                        // 400 KB

    hipMemsetAsync(cnt, 0, N_NODES * sizeof(int), stream);

    int cblocks = (int)(((size_t)N_NODES * D / 4 + 255) / 256); // 12500
    int epb = (n_edges + cblocks - 1) / cblocks;                // 128
    hipLaunchKernelGGL(prep_k, dim3(cblocks + 16), dim3(256), 0, stream,
                       h, h_bf, W, Wf, src, dst, cnt, pairs, n_edges, cblocks, epb);

    hipLaunchKernelGGL(aggemm_k, dim3(NB), dim3(512), 0, stream,
                       h_bf, pairs, cnt, Wf, b, out);
}

// Round 8
// 227.804 us; speedup vs baseline: 5.9672x; 1.1638x over previous
//
#include <hip/hip_runtime.h>
#include <stdint.h>

#define N_NODES 100000
#define D 128
#define BN 64                        // nodes per bucket / GEMM row tile
#define NB ((N_NODES + BN - 1) / BN) // 1563 buckets
#define EPB 4096                     // edges per partition block
#define CAP 1536                     // per-bucket capacity (mean 1024, sigma~32 -> 16 sigma)
#define HPAD 136                     // hNs row stride in ushorts (272B: 2-way max on b128 = free)

typedef short bf16x8 __attribute__((ext_vector_type(8)));
typedef float f32x4 __attribute__((ext_vector_type(4)));

__device__ __forceinline__ unsigned short f2bf(float f) {
    unsigned int x = __float_as_uint(f);
    unsigned int r = x + 0x7fffu + ((x >> 16) & 1u);
    return (unsigned short)(r >> 16);
}
__device__ __forceinline__ float blo(unsigned int u) { return __uint_as_float(u << 16); }
__device__ __forceinline__ float bhi(unsigned int u) { return __uint_as_float(u & 0xffff0000u); }

// ---- fused prep -----------------------------------------------------------
// [0,partb): two-level bucket partition. LDS hist over 1563 buckets ->
//            ONE global atomic per nonzero (block,bucket) (~0.57M total,
//            vs 1.6M per-edge atomics that capped R7 at ~17 atomics/ns).
//            Bucket-run writes restore partial write coalescing.
// [partb,partb+16): W-pack.   [partb+16,...): h fp32 -> bf16 conv.
__global__ __launch_bounds__(256) void prep_k(
    const float* __restrict__ h, unsigned short* __restrict__ h_bf,
    const float* __restrict__ W, unsigned short* __restrict__ Wf,
    const int* __restrict__ src, const int* __restrict__ dst,
    int* __restrict__ cnt, unsigned int* __restrict__ pairs,
    int n_edges, int partb)
{
    __shared__ int hist[NB];   // counts, then reused as global base
    __shared__ int lc[NB];     // local running cursor

    int bid = blockIdx.x;
    int t = threadIdx.x;

    if (bid < partb) {
        for (int i = t; i < NB; i += 256) { hist[i] = 0; lc[i] = 0; }
        __syncthreads();
        int base = bid * EPB;
        int lim = n_edges - base; if (lim > EPB) lim = EPB; if (lim < 0) lim = 0;
        for (int i = t; i < lim; i += 256)
            atomicAdd(&hist[dst[base + i] >> 6], 1);
        __syncthreads();
        for (int i = t; i < NB; i += 256) {
            int c = hist[i];
            hist[i] = c ? atomicAdd(&cnt[i], c) : 0;   // global base for this block
        }
        __syncthreads();
        for (int i = t; i < lim; i += 256) {
            int e = base + i;
            int d = dst[e], b = d >> 6;
            int slot = atomicAdd(&lc[b], 1);           // LDS atomic
            int off = hist[b] + slot;
            if (off < CAP)
                pairs[(size_t)b * CAP + off] =
                    (unsigned int)src[e] | ((unsigned int)(d & 63) << 17);
        }
    } else if (bid < partb + 16) {
        // ---- pack W [256][128] fp32 -> bf16 B-fragment order ----
        // frag f = kt*8+ct; lane l holds W[kt*32+(l>>4)*8+j][ct*16+(l&15)]
        int gid = (bid - partb) * 256 + t;
        if (gid < 64 * 64) {
            int f = gid >> 6, l = gid & 63;
            int kt = f >> 3, ct = f & 7;
            int n = ct * 16 + (l & 15);
            int kb = kt * 32 + (l >> 4) * 8;
            #pragma unroll
            for (int j = 0; j < 8; ++j)
                Wf[(size_t)f * 512 + l * 8 + j] = f2bf(W[(size_t)(kb + j) * D + n]);
        }
    } else {
        // ---- h fp32 -> bf16 ----
        size_t base = ((size_t)(bid - partb - 16) * 256 + t) * 4;
        if (base < (size_t)N_NODES * D) {
            float4 v = *(const float4*)(h + base);
            ushort4 o;
            o.x = f2bf(v.x); o.y = f2bf(v.y); o.z = f2bf(v.z); o.w = f2bf(v.w);
            *(ushort4*)(h_bf + base) = o;
        }
    }
}

// ---- fused aggregate + GEMM: block = bucket of 64 nodes, 512 threads ------
// 1) stage bucket pairs -> LDS + hist; scan; scatter -> node-sorted srt
//    (indices end up in LDS: removes the per-node global index-load latency
//    that cost R6 ~6us vs R4)
// 2) QUARTER-wave dwordx4 gather: 16 lanes x 16B = one 256B row; one
//    wave-instr = 4 edges; unroll 4 -> 16 row-loads in flight per wave
// 3) 8-wave MFMA: out[64][128] = [h_row | hNs] @ W + b
__global__ __launch_bounds__(512, 8) void aggemm_k(
    const unsigned short* __restrict__ h_bf, const unsigned int* __restrict__ pairs,
    const int* __restrict__ cnt_g, const unsigned short* __restrict__ Wf,
    const float* __restrict__ bias, float* __restrict__ out)
{
    __shared__ unsigned int lp[CAP];          // 6 KB staged pairs
    __shared__ unsigned int srt[CAP];         // 6 KB node-sorted src indices
    __shared__ int counts[BN];
    __shared__ int startp[BN];
    __shared__ int cursor[BN];
    __shared__ unsigned short hNs[BN][HPAD];  // 17.4 KB bf16 hN tile

    int t = threadIdx.x;
    int b = blockIdx.x;
    int wv = t >> 6, l = t & 63;
    size_t e0 = (size_t)b * CAP;
    int cnt = cnt_g[b];
    if (cnt > CAP) cnt = CAP;   // overflow guard; never hit for random dst

    if (t < BN) counts[t] = 0;
    __syncthreads();

    // stage + local histogram
    for (int i = t; i < cnt; i += 512) {
        unsigned int p = pairs[e0 + i];
        lp[i] = p;
        atomicAdd(&counts[p >> 17], 1);
    }
    __syncthreads();

    // exclusive scan of counts[64] (Hillis-Steele; barriers unconditional)
    if (t < BN) startp[t] = counts[t];
    __syncthreads();
    #pragma unroll
    for (int off = 1; off < BN; off <<= 1) {
        int v = 0;
        if (t < BN && t >= off) v = startp[t - off];
        __syncthreads();
        if (t < BN) startp[t] += v;
        __syncthreads();
    }
    if (t < BN) {
        int ex = startp[t] - counts[t];
        startp[t] = ex;
        cursor[t] = ex;
    }
    __syncthreads();

    // scatter into node-sorted order (all LDS)
    for (int i = t; i < cnt; i += 512) {
        unsigned int p = lp[i];
        int s = atomicAdd(&cursor[p >> 17], 1);
        srt[s] = p & 0x1FFFFu;
    }
    __syncthreads();

    // gather: quarter-wave q of wave wv -> local node p2*32 + wv*4 + q
    int q = l >> 4, lq = l & 15;     // lane lq covers features 8lq..8lq+7
    int nbase = b * BN;
    #pragma unroll
    for (int p2 = 0; p2 < 2; ++p2) {
        int nl = p2 * 32 + wv * 4 + q;
        int dg = counts[nl], s0 = startp[nl];   // 0 for nodes >= N_NODES
        float a0 = 0.f, a1 = 0.f, a2 = 0.f, a3 = 0.f;
        float a4 = 0.f, a5 = 0.f, a6 = 0.f, a7 = 0.f;
        int i = 0;
        for (; i + 4 <= dg; i += 4) {           // 4 row-loads in flight/quarter
            int s0i = srt[s0 + i],     s1i = srt[s0 + i + 1];
            int s2i = srt[s0 + i + 2], s3i = srt[s0 + i + 3];
            uint4 u0 = *(const uint4*)(h_bf + (size_t)s0i * D + lq * 8);
            uint4 u1 = *(const uint4*)(h_bf + (size_t)s1i * D + lq * 8);
            uint4 u2 = *(const uint4*)(h_bf + (size_t)s2i * D + lq * 8);
            uint4 u3 = *(const uint4*)(h_bf + (size_t)s3i * D + lq * 8);
            a0 += (blo(u0.x) + blo(u1.x)) + (blo(u2.x) + blo(u3.x));
            a1 += (bhi(u0.x) + bhi(u1.x)) + (bhi(u2.x) + bhi(u3.x));
            a2 += (blo(u0.y) + blo(u1.y)) + (blo(u2.y) + blo(u3.y));
            a3 += (bhi(u0.y) + bhi(u1.y)) + (bhi(u2.y) + bhi(u3.y));
            a4 += (blo(u0.z) + blo(u1.z)) + (blo(u2.z) + blo(u3.z));
            a5 += (bhi(u0.z) + bhi(u1.z)) + (bhi(u2.z) + bhi(u3.z));
            a6 += (blo(u0.w) + blo(u1.w)) + (blo(u2.w) + blo(u3.w));
            a7 += (bhi(u0.w) + bhi(u1.w)) + (bhi(u2.w) + bhi(u3.w));
        }
        for (; i < dg; ++i) {
            uint4 u = *(const uint4*)(h_bf + (size_t)srt[s0 + i] * D + lq * 8);
            a0 += blo(u.x); a1 += bhi(u.x);
            a2 += blo(u.y); a3 += bhi(u.y);
            a4 += blo(u.z); a5 += bhi(u.z);
            a6 += blo(u.w); a7 += bhi(u.w);
        }
        float invd = dg > 0 ? 1.0f / (float)dg : 0.f;
        uint4 o;
        o.x = ((unsigned int)f2bf(a1 * invd) << 16) | f2bf(a0 * invd);
        o.y = ((unsigned int)f2bf(a3 * invd) << 16) | f2bf(a2 * invd);
        o.z = ((unsigned int)f2bf(a5 * invd) << 16) | f2bf(a4 * invd);
        o.w = ((unsigned int)f2bf(a7 * invd) << 16) | f2bf(a6 * invd);
        *(uint4*)(&hNs[nl][lq * 8]) = o;   // LDS only; never goes to HBM
    }
    __syncthreads();

    // ---- GEMM: wave wv -> row-tile (wv>>1), col-half (wv&1) ---------------
    int rt = wv >> 1, ch = wv & 1;
    int lrow = l & 15, lqd = l >> 4;
    int lr = rt * 16 + lrow;                       // local A row
    int r0 = nbase + lr; if (r0 > N_NODES - 1) r0 = N_NODES - 1;

    f32x4 acc[4];
    #pragma unroll
    for (int c = 0; c < 4; ++c) acc[c] = (f32x4){0.f, 0.f, 0.f, 0.f};

    const unsigned short* wf_lane = Wf + l * 8;

    #pragma unroll
    for (int kt = 0; kt < 8; ++kt) {
        int ko = (kt & 3) * 32 + lqd * 8;
        bf16x8 a;
        if (kt < 4)
            a = *(const bf16x8*)(h_bf + (size_t)r0 * D + ko);   // self features
        else
            a = *(const bf16x8*)(&hNs[lr][ko]);                 // neighbor mean
        #pragma unroll
        for (int c = 0; c < 4; ++c) {
            int ct = ch * 4 + c;
            bf16x8 bfr = *(const bf16x8*)(wf_lane + (size_t)(kt * 8 + ct) * 512);
            acc[c] = __builtin_amdgcn_mfma_f32_16x16x32_bf16(a, bfr, acc[c], 0, 0, 0);
        }
    }

    int col = l & 15, qd = l >> 4;
    #pragma unroll
    for (int c = 0; c < 4; ++c) {
        int ct = ch * 4 + c;
        float bv = bias[ct * 16 + col];
        #pragma unroll
        for (int r = 0; r < 4; ++r) {
            int row = nbase + rt * 16 + qd * 4 + r;
            if (row < N_NODES)
                out[(size_t)row * D + ct * 16 + col] = acc[c][r] + bv;
        }
    }
}

// ---- launch ---------------------------------------------------------------

extern "C" void kernel_launch(void* const* d_in, const int* in_sizes, int n_in,
                              void* d_out, int out_size, void* d_ws, size_t ws_size,
                              hipStream_t stream) {
    const float* h  = (const float*)d_in[0];
    const int* src  = (const int*)d_in[1];
    const int* dst  = (const int*)d_in[2];
    const float* W  = (const float*)d_in[3];
    const float* b  = (const float*)d_in[4];
    float* out      = (float*)d_out;
    int n_edges = in_sizes[1];

    // workspace layout (~35.3 MB)
    char* ws = (char*)d_ws;
    unsigned short* h_bf  = (unsigned short*)ws;                          // 25.6 MB
    unsigned int* pairs   = (unsigned int*)(h_bf + (size_t)N_NODES * D);  // 9.6 MB (NB*CAP*4)
    unsigned short* Wf    = (unsigned short*)(pairs + (size_t)NB * CAP);  // 64 KB
    int* cnt              = (int*)(Wf + 64 * 512);                        // 6.3 KB

    hipMemsetAsync(cnt, 0, NB * sizeof(int), stream);

    int partb = (n_edges + EPB - 1) / EPB;                      // 391
    int cblocks = (int)(((size_t)N_NODES * D / 4 + 255) / 256); // 12500
    hipLaunchKernelGGL(prep_k, dim3(partb + 16 + cblocks), dim3(256), 0, stream,
                       h, h_bf, W, Wf, src, dst, cnt, pairs, n_edges, partb);

    hipLaunchKernelGGL(aggemm_k, dim3(NB), dim3(512), 0, stream,
                       h_bf, pairs, cnt, Wf, b, out);
}

// Round 9
// 222.066 us; speedup vs baseline: 6.1213x; 1.0258x over previous
//
#include <hip/hip_runtime.h>
#include <stdint.h>

#define N_NODES 100000
#define D 128
#define BN 64                        // nodes per bucket / GEMM row tile
#define NB ((N_NODES + BN - 1) / BN) // 1563 buckets
#define EPB 4096                     // edges per partition block
#define NR 4                         // cnt replicas per bucket (chain depth 391 -> 98)
#define CAPR 448                     // per-(bucket,replica) capacity (mean 256, sigma 16 -> 12 sigma)
#define CAP 1536                     // staged per-bucket capacity (mean 1024, 16 sigma)
#define HPAD 136                     // hNs row stride in ushorts (272B)
#define NK 512                       // sort keys: 64 nodes x 8 src-octants

typedef short bf16x8 __attribute__((ext_vector_type(8)));
typedef float f32x4 __attribute__((ext_vector_type(4)));

__device__ __forceinline__ unsigned short f2bf(float f) {
    unsigned int x = __float_as_uint(f);
    unsigned int r = x + 0x7fffu + ((x >> 16) & 1u);
    return (unsigned short)(r >> 16);
}
__device__ __forceinline__ float blo(unsigned int u) { return __uint_as_float(u << 16); }
__device__ __forceinline__ float bhi(unsigned int u) { return __uint_as_float(u & 0xffff0000u); }

// ---- fused prep -----------------------------------------------------------
// [0,partb): two-level bucket partition (LDS hist -> one global atomic per
//            nonzero (block,bucket), on replica bid&3 -> 98-deep chains).
// [partb,partb+16): W-pack.   [partb+16,...): h fp32 -> bf16 conv.
__global__ __launch_bounds__(256) void prep_k(
    const float* __restrict__ h, unsigned short* __restrict__ h_bf,
    const float* __restrict__ W, unsigned short* __restrict__ Wf,
    const int* __restrict__ src, const int* __restrict__ dst,
    int* __restrict__ cnt, unsigned int* __restrict__ pairs,
    int n_edges, int partb)
{
    __shared__ int hist[NB];   // counts, then reused as global base
    __shared__ int lc[NB];     // local running cursor

    int bid = blockIdx.x;
    int t = threadIdx.x;

    if (bid < partb) {
        for (int i = t; i < NB; i += 256) { hist[i] = 0; lc[i] = 0; }
        __syncthreads();
        int base = bid * EPB;
        int lim = n_edges - base; if (lim > EPB) lim = EPB; if (lim < 0) lim = 0;
        for (int i = t; i < lim; i += 256)
            atomicAdd(&hist[dst[base + i] >> 6], 1);
        __syncthreads();
        int rep = bid & (NR - 1);
        for (int i = t; i < NB; i += 256) {
            int c = hist[i];
            hist[i] = c ? atomicAdd(&cnt[i * NR + rep], c) : 0;  // base in replica seg
        }
        __syncthreads();
        for (int i = t; i < lim; i += 256) {
            int e = base + i;
            int d = dst[e], b = d >> 6;
            int slot = atomicAdd(&lc[b], 1);           // LDS atomic
            int off = hist[b] + slot;
            if (off < CAPR)
                pairs[((size_t)b * NR + rep) * CAPR + off] =
                    (unsigned int)src[e] | ((unsigned int)(d & 63) << 17);
        }
    } else if (bid < partb + 16) {
        // ---- pack W [256][128] fp32 -> bf16 B-fragment order ----
        int gid = (bid - partb) * 256 + t;
        if (gid < 64 * 64) {
            int f = gid >> 6, l = gid & 63;
            int kt = f >> 3, ct = f & 7;
            int n = ct * 16 + (l & 15);
            int kb = kt * 32 + (l >> 4) * 8;
            #pragma unroll
            for (int j = 0; j < 8; ++j)
                Wf[(size_t)f * 512 + l * 8 + j] = f2bf(W[(size_t)(kb + j) * D + n]);
        }
    } else {
        // ---- h fp32 -> bf16 ----
        size_t base = ((size_t)(bid - partb - 16) * 256 + t) * 4;
        if (base < (size_t)N_NODES * D) {
            float4 v = *(const float4*)(h + base);
            ushort4 o;
            o.x = f2bf(v.x); o.y = f2bf(v.y); o.z = f2bf(v.z); o.w = f2bf(v.w);
            *(ushort4*)(h_bf + base) = o;
        }
    }
}

// ---- fused aggregate + GEMM: block = bucket of 64 nodes, 512 threads ------
// 1) stage 4 replica segments -> LDS; hist on key = (node<<3)|src_octant
//    (= p>>14); 512-entry scan; scatter -> srt sorted by (node, octant).
//    Octant-sorted lists make all co-resident blocks sweep the same ~4MB
//    src window in phase -> gather hits L2 instead of thrashing to L3/HBM.
// 2) quarter-wave dwordx4 gather (16 lanes x 16B = one 256B row; 4 edges
//    per wave-instr, 16 row-loads in flight per wave)
// 3) 8-wave MFMA: out[64][128] = [h_row | hNs] @ W + b
__global__ __launch_bounds__(512, 8) void aggemm_k(
    const unsigned short* __restrict__ h_bf, const unsigned int* __restrict__ pairs,
    const int* __restrict__ cnt_g, const unsigned short* __restrict__ Wf,
    const float* __restrict__ bias, float* __restrict__ out)
{
    __shared__ unsigned int lp[CAP];          // 6 KB staged pairs
    __shared__ unsigned int srt[CAP];         // 6 KB (node,octant)-sorted src idx
    __shared__ int cnt2[NK];                  // 2 KB key histogram
    __shared__ int ps[NK];                    // 2 KB scan workspace
    __shared__ int cur2[NK];                  // 2 KB scatter cursors
    __shared__ int counts[BN];
    __shared__ int startp[BN];
    __shared__ unsigned short hNs[BN][HPAD];  // 17.4 KB bf16 hN tile

    int t = threadIdx.x;
    int b = blockIdx.x;
    int wv = t >> 6, l = t & 63;

    // segment offsets (redundant per-thread; no barrier needed)
    int segc[NR], sego[NR];
    {
        int tot = 0;
        #pragma unroll
        for (int r = 0; r < NR; ++r) {
            int c = cnt_g[b * NR + r];
            if (c > CAPR) c = CAPR;
            if (tot + c > CAP) c = CAP - tot;
            sego[r] = tot; segc[r] = c; tot += c;
        }
    }

    cnt2[t] = 0;
    __syncthreads();

    // stage + key histogram (key = p>>14 = node*8 + src[16:14])
    #pragma unroll
    for (int r = 0; r < NR; ++r) {
        const unsigned int* psg = pairs + ((size_t)b * NR + r) * CAPR;
        int c = segc[r], o = sego[r];
        for (int i = t; i < c; i += 512) {
            unsigned int p = psg[i];
            lp[o + i] = p;
            atomicAdd(&cnt2[p >> 14], 1);
        }
    }
    int cnt = sego[NR - 1] + segc[NR - 1];
    __syncthreads();

    // exclusive scan over 512 keys (Hillis-Steele, all threads participate)
    ps[t] = cnt2[t];
    __syncthreads();
    #pragma unroll
    for (int off = 1; off < NK; off <<= 1) {
        int v = (t >= off) ? ps[t - off] : 0;
        __syncthreads();
        ps[t] += v;
        __syncthreads();
    }
    int excl = ps[t] - cnt2[t];
    cur2[t] = excl;
    if ((t & 7) == 0) startp[t >> 3] = excl;
    __syncthreads();
    if ((t & 7) == 7) counts[t >> 3] = ps[t] - startp[t >> 3];
    __syncthreads();

    // scatter into (node, octant)-sorted order (all LDS)
    for (int i = t; i < cnt; i += 512) {
        unsigned int p = lp[i];
        int s = atomicAdd(&cur2[p >> 14], 1);
        srt[s] = p & 0x1FFFFu;
    }
    __syncthreads();

    // gather: quarter-wave q of wave wv -> local node p2*32 + wv*4 + q
    int q = l >> 4, lq = l & 15;     // lane lq covers features 8lq..8lq+7
    int nbase = b * BN;
    #pragma unroll
    for (int p2 = 0; p2 < 2; ++p2) {
        int nl = p2 * 32 + wv * 4 + q;
        int dg = counts[nl], s0 = startp[nl];   // 0 for nodes >= N_NODES
        float a0 = 0.f, a1 = 0.f, a2 = 0.f, a3 = 0.f;
        float a4 = 0.f, a5 = 0.f, a6 = 0.f, a7 = 0.f;
        int i = 0;
        for (; i + 4 <= dg; i += 4) {           // 4 row-loads in flight/quarter
            int s0i = srt[s0 + i],     s1i = srt[s0 + i + 1];
            int s2i = srt[s0 + i + 2], s3i = srt[s0 + i + 3];
            uint4 u0 = *(const uint4*)(h_bf + (size_t)s0i * D + lq * 8);
            uint4 u1 = *(const uint4*)(h_bf + (size_t)s1i * D + lq * 8);
            uint4 u2 = *(const uint4*)(h_bf + (size_t)s2i * D + lq * 8);
            uint4 u3 = *(const uint4*)(h_bf + (size_t)s3i * D + lq * 8);
            a0 += (blo(u0.x) + blo(u1.x)) + (blo(u2.x) + blo(u3.x));
            a1 += (bhi(u0.x) + bhi(u1.x)) + (bhi(u2.x) + bhi(u3.x));
            a2 += (blo(u0.y) + blo(u1.y)) + (blo(u2.y) + blo(u3.y));
            a3 += (bhi(u0.y) + bhi(u1.y)) + (bhi(u2.y) + bhi(u3.y));
            a4 += (blo(u0.z) + blo(u1.z)) + (blo(u2.z) + blo(u3.z));
            a5 += (bhi(u0.z) + bhi(u1.z)) + (bhi(u2.z) + bhi(u3.z));
            a6 += (blo(u0.w) + blo(u1.w)) + (blo(u2.w) + blo(u3.w));
            a7 += (bhi(u0.w) + bhi(u1.w)) + (bhi(u2.w) + bhi(u3.w));
        }
        for (; i < dg; ++i) {
            uint4 u = *(const uint4*)(h_bf + (size_t)srt[s0 + i] * D + lq * 8);
            a0 += blo(u.x); a1 += bhi(u.x);
            a2 += blo(u.y); a3 += bhi(u.y);
            a4 += blo(u.z); a5 += bhi(u.z);
            a6 += blo(u.w); a7 += bhi(u.w);
        }
        float invd = dg > 0 ? 1.0f / (float)dg : 0.f;
        uint4 o;
        o.x = ((unsigned int)f2bf(a1 * invd) << 16) | f2bf(a0 * invd);
        o.y = ((unsigned int)f2bf(a3 * invd) << 16) | f2bf(a2 * invd);
        o.z = ((unsigned int)f2bf(a5 * invd) << 16) | f2bf(a4 * invd);
        o.w = ((unsigned int)f2bf(a7 * invd) << 16) | f2bf(a6 * invd);
        *(uint4*)(&hNs[nl][lq * 8]) = o;   // LDS only; never goes to HBM
    }
    __syncthreads();

    // ---- GEMM: wave wv -> row-tile (wv>>1), col-half (wv&1) ---------------
    int rt = wv >> 1, ch = wv & 1;
    int lrow = l & 15, lqd = l >> 4;
    int lr = rt * 16 + lrow;                       // local A row
    int r0 = nbase + lr; if (r0 > N_NODES - 1) r0 = N_NODES - 1;

    f32x4 acc[4];
    #pragma unroll
    for (int c = 0; c < 4; ++c) acc[c] = (f32x4){0.f, 0.f, 0.f, 0.f};

    const unsigned short* wf_lane = Wf + l * 8;

    #pragma unroll
    for (int kt = 0; kt < 8; ++kt) {
        int ko = (kt & 3) * 32 + lqd * 8;
        bf16x8 a;
        if (kt < 4)
            a = *(const bf16x8*)(h_bf + (size_t)r0 * D + ko);   // self features
        else
            a = *(const bf16x8*)(&hNs[lr][ko]);                 // neighbor mean
        #pragma unroll
        for (int c = 0; c < 4; ++c) {
            int ct = ch * 4 + c;
            bf16x8 bfr = *(const bf16x8*)(wf_lane + (size_t)(kt * 8 + ct) * 512);
            acc[c] = __builtin_amdgcn_mfma_f32_16x16x32_bf16(a, bfr, acc[c], 0, 0, 0);
        }
    }

    int col = l & 15, qd = l >> 4;
    #pragma unroll
    for (int c = 0; c < 4; ++c) {
        int ct = ch * 4 + c;
        float bv = bias[ct * 16 + col];
        #pragma unroll
        for (int r = 0; r < 4; ++r) {
            int row = nbase + rt * 16 + qd * 4 + r;
            if (row < N_NODES)
                out[(size_t)row * D + ct * 16 + col] = acc[c][r] + bv;
        }
    }
}

// ---- launch ---------------------------------------------------------------

extern "C" void kernel_launch(void* const* d_in, const int* in_sizes, int n_in,
                              void* d_out, int out_size, void* d_ws, size_t ws_size,
                              hipStream_t stream) {
    const float* h  = (const float*)d_in[0];
    const int* src  = (const int*)d_in[1];
    const int* dst  = (const int*)d_in[2];
    const float* W  = (const float*)d_in[3];
    const float* b  = (const float*)d_in[4];
    float* out      = (float*)d_out;
    int n_edges = in_sizes[1];

    // workspace layout (~37 MB)
    char* ws = (char*)d_ws;
    unsigned short* h_bf  = (unsigned short*)ws;                          // 25.6 MB
    unsigned int* pairs   = (unsigned int*)(h_bf + (size_t)N_NODES * D);  // 11.2 MB (NB*NR*CAPR*4)
    unsigned short* Wf    = (unsigned short*)(pairs + (size_t)NB * NR * CAPR); // 64 KB
    int* cnt              = (int*)(Wf + 64 * 512);                        // 25 KB

    hipMemsetAsync(cnt, 0, NB * NR * sizeof(int), stream);

    int partb = (n_edges + EPB - 1) / EPB;                      // 391
    int cblocks = (int)(((size_t)N_NODES * D / 4 + 255) / 256); // 12500
    hipLaunchKernelGGL(prep_k, dim3(partb + 16 + cblocks), dim3(256), 0, stream,
                       h, h_bf, W, Wf, src, dst, cnt, pairs, n_edges, partb);

    hipLaunchKernelGGL(aggemm_k, dim3(NB), dim3(512), 0, stream,
                       h_bf, pairs, cnt, Wf, b, out);
}